// Round 19
// baseline (2947.942 us; speedup 1.0000x reference)
//
#include <hip/hip_runtime.h>

// RNN: s_{t+1} = 0.9*s + 0.1*(relu(s@Wrec^T + (u+inz)@Winp^T) + rn)
// d_out = states (B,T,N) fp32 then outputs (B,T,1) fp32, flat-concat.
//
// R19 = R18 (fused tag+payload IF exchange, paired polls, 2.63 ms) +
// PREFETCHED POLLS: reader ISSUES next step's poll loads right after its
// own publish (plain __hip_atomic_load SYSTEM -> compiler defers the
// s_waitcnt to first use = next iteration's tag check), so the ~1us IF
// flight overlaps the loop tail instead of sitting on the critical path.
// Words are self-validating (tag<<32|fp32), so a too-early prefetch just
// fails the tag check and falls back to R18's proven blocking xld4
// re-poll -- no protocol change, no liveness risk. asm "memory" fence
// after the prefetch pins the issue point (no sinking to first use).
// Everything else identical to R18/R15: PP=4 x 64 groups x GG=2;
// W slice (128 floats/thread) pinned in VGPRs by in-loop scalar asm;
// xbuf parity double-buffer (WAR-safe 2-deep); 2 barriers/step; init
// kernel resets tags to -1 (0xAA poison parses negative) -> replay-safe.
// out_proj projects outputs afterwards. Fallback R1-style kernel if ws
// is too small (< 1 MB).

#define NN 512
#define BB 128
#define TT 1000
#define NIN 6
#define PP 4                    // n-slices (WGs per group)
#define GG 2                    // batches per group
#define NGRP (BB / GG)          // 64 groups
#define NWG (PP * NGRP)         // 256 workgroups
#define SLICE (NN / PP)         // 128
#define XWORDS (2 * NGRP * GG * NN)          // 131072 words = 1 MB
#define WS_NEED (XWORDS * sizeof(unsigned long long))

typedef unsigned long long u64;
typedef unsigned int u32x4 __attribute__((ext_vector_type(4)));

__global__ void init_xbuf(u64* xbuf) {
  const int i = blockIdx.x * 256 + threadIdx.x;
  if (i < XWORDS) xbuf[i] = 0xFFFFFFFF00000000ULL;  // tag = -1
}

__device__ __forceinline__ float wave_sum(float v) {
  #pragma unroll
  for (int off = 32; off > 0; off >>= 1) v += __shfl_xor(v, off, 64);
  return v;
}

// empty asm with tied SCALAR outputs: values become opaque (non-remat).
__device__ __forceinline__ void pin4(float4& a, float4& b, float4& c, float4& d) {
  asm volatile("" : "+v"(a.x), "+v"(a.y), "+v"(a.z), "+v"(a.w),
                    "+v"(b.x), "+v"(b.y), "+v"(b.z), "+v"(b.w),
                    "+v"(c.x), "+v"(c.y), "+v"(c.z), "+v"(c.w),
                    "+v"(d.x), "+v"(d.y), "+v"(d.z), "+v"(d.w));
}

// system-scope relaxed u64 (sc0sc1 -> IF, chip-coherent). R12-proven.
__device__ __forceinline__ u64 xld(const u64* p) {
  return __hip_atomic_load(p, __ATOMIC_RELAXED, __HIP_MEMORY_SCOPE_SYSTEM);
}
__device__ __forceinline__ void xst(u64* p, u64 v) {
  __hip_atomic_store(p, v, __ATOMIC_RELAXED, __HIP_MEMORY_SCOPE_SYSTEM);
}
// blocking paired poll: 16B system-scope load of two adjacent words.
// v.x/v.y = payload/tag of word0; v.z/v.w = payload/tag of word1.
__device__ __forceinline__ u32x4 xld4(const u64* p) {
  u32x4 v;
  asm volatile("global_load_dwordx4 %0, %1, off sc0 sc1\n\ts_waitcnt vmcnt(0)"
               : "=v"(v) : "v"(p) : "memory");
  return v;
}

__global__ __launch_bounds__(512, 1)
void rnn_tagx6(const float* __restrict__ u, const float* __restrict__ rnz,
               const float* __restrict__ inz, const float* __restrict__ Wrec,
               const float* __restrict__ Winp, const float* __restrict__ yinit,
               float* __restrict__ states, u64* __restrict__ xbuf) {
  const int tid = threadIdx.x;
  // bid remap: group's 4 WGs share bid&7 (locality hint only; protocol
  // is placement-independent -- all exchange goes through IF).
  const int xcd = blockIdx.x & 7;
  const int rest = blockIdx.x >> 3;     // 0..31
  const int p = rest & 3;               // my n-slice
  const int g = (rest >> 2) * 8 + xcd;  // my group 0..63

  // phase-A mapping: thread (nq, ks) = 4 n-rows x 32-k window x 2 batches
  const int nq = tid & 31;
  const int n0 = nq << 2;               // local n base
  const int ks = tid >> 5;              // k-split 0..15 (wave-uniform x2)
  const int k0 = ks << 5;               // global k base
  // update mapping (tid < 256): thread = (batch, local n)  [R15 verbatim]
  const int ub = (tid >> 7) & 1;
  const int un = tid & 127;
  const int ung = p * SLICE + un;
  // fetch decode (tid < 384): rank r = tid>>7 -> peer slice q=(p+1+r)&3;
  // rem = tid&127: batch = rem>>6, n-pair base = (rem&63)*2
  const int fq = (p + 1 + (tid >> 7)) & 3;
  const int rem = tid & 127;
  const int fb = rem >> 6;
  const int fn = (rem & 63) << 1;
  // parity poll pointers (t-invariant)
  const u64* pp0 = xbuf + (size_t)g * GG * NN + (size_t)fb * NN + fq * SLICE + fn;
  const u64* pp1 = pp0 + (size_t)NGRP * GG * NN;

  __shared__ __align__(16) float pred[16][GG][SLICE];  // 16 KB
  __shared__ __align__(16) float s_all[GG][NN];        // 4 KB
  __shared__ float winp_s[SLICE][NIN];                 // 3 KB
  __shared__ float ubuf[2][GG][NIN];                   // parity-buffered

  // ---- one-time: W fragment (4 rows x 32 k), Winp ----
  float4 w[4][8];
  #pragma unroll
  for (int i = 0; i < 4; ++i) {
    const float* wr = Wrec + (size_t)(p * SLICE + n0 + i) * NN + k0;
    #pragma unroll
    for (int q = 0; q < 8; ++q)
      w[i][q] = *reinterpret_cast<const float4*>(wr + 4 * q);
  }
  for (int i = tid; i < SLICE * NIN; i += 512) {
    const int r = i / NIN, j = i - r * NIN;
    winp_s[r][j] = Winp[(p * SLICE + r) * NIN + j];
  }
  // s_0 = y_init everywhere (local knowledge: no exchange needed at t=0)
  for (int i = tid; i < GG * NN; i += 512)
    s_all[i >> 9][i & 511] = yinit[i & 511];
  for (int i = tid; i < GG * NN; i += 512)
    states[(size_t)(g * GG + (i >> 9)) * TT * NN + (i & 511)] = yinit[i & 511];
  float scur = (tid < 256) ? yinit[ung] : 0.f;
  u64 pfa = 0, pfb = 0;  // prefetched words (tag 0 -> forces poll if unset)
  __syncthreads();

  for (int t = 0; t < TT - 1; ++t) {
    const int par = t & 1;

    // pin W live (R6: unpinned W was re-streamed from L2 every step)
    #pragma unroll
    for (int i = 0; i < 4; ++i) {
      pin4(w[i][0], w[i][1], w[i][2], w[i][3]);
      pin4(w[i][4], w[i][5], w[i][6], w[i][7]);
    }

    // early per-step loads (plain, cached; consumed after barB)
    float rnv = 0.f;
    if (tid < 256)
      rnv = rnz[((size_t)(g * GG + ub) * TT + t) * NN + ung];
    if (tid < GG * NIN) {
      const int b = tid / NIN, j = tid - b * NIN;
      const size_t idx = ((size_t)(g * GG + b) * TT + t) * NIN + j;
      ubuf[par][b][j] = u[idx] + inz[idx];
    }

    // ---- fetch: prefetched words first; blocking re-poll on miss ----
    if (t > 0 && tid < 384) {
      u64 va = pfa, vb = pfb;  // s_waitcnt for the prefetch lands here
      if ((int)(va >> 32) < t || (int)(vb >> 32) < t) {
        const u64* pp = par ? pp1 : pp0;
        u32x4 v = xld4(pp);
        while ((int)v.y < t || (int)v.w < t) {
          __builtin_amdgcn_s_sleep(1);
          v = xld4(pp);
        }
        va = ((u64)v.y << 32) | v.x;
        vb = ((u64)v.w << 32) | v.z;
      }
      *reinterpret_cast<float2*>(&s_all[fb][fq * SLICE + fn]) =
          make_float2(__uint_as_float((unsigned)va),
                      __uint_as_float((unsigned)vb));
    }
    __syncthreads();  // barA: s_all complete (own slice from last update)

    // ---- phase A: 4 n x 32 k x 2 b partial dots (256 fmaf) ----
    float a0[GG], a1[GG], a2[GG], a3[GG];
    #pragma unroll
    for (int b = 0; b < GG; ++b) { a0[b] = 0.f; a1[b] = 0.f; a2[b] = 0.f; a3[b] = 0.f; }
    #pragma unroll
    for (int b = 0; b < GG; ++b) {
      #pragma unroll
      for (int q = 0; q < 8; ++q) {
        const float4 sv = *reinterpret_cast<const float4*>(&s_all[b][k0 + 4 * q]);
        a0[b] = fmaf(w[0][q].x, sv.x, a0[b]); a0[b] = fmaf(w[0][q].y, sv.y, a0[b]);
        a0[b] = fmaf(w[0][q].z, sv.z, a0[b]); a0[b] = fmaf(w[0][q].w, sv.w, a0[b]);
        a1[b] = fmaf(w[1][q].x, sv.x, a1[b]); a1[b] = fmaf(w[1][q].y, sv.y, a1[b]);
        a1[b] = fmaf(w[1][q].z, sv.z, a1[b]); a1[b] = fmaf(w[1][q].w, sv.w, a1[b]);
        a2[b] = fmaf(w[2][q].x, sv.x, a2[b]); a2[b] = fmaf(w[2][q].y, sv.y, a2[b]);
        a2[b] = fmaf(w[2][q].z, sv.z, a2[b]); a2[b] = fmaf(w[2][q].w, sv.w, a2[b]);
        a3[b] = fmaf(w[3][q].x, sv.x, a3[b]); a3[b] = fmaf(w[3][q].y, sv.y, a3[b]);
        a3[b] = fmaf(w[3][q].z, sv.z, a3[b]); a3[b] = fmaf(w[3][q].w, sv.w, a3[b]);
      }
    }
    #pragma unroll
    for (int b = 0; b < GG; ++b)
      *reinterpret_cast<float4*>(&pred[ks][b][n0]) =
          make_float4(a0[b], a1[b], a2[b], a3[b]);
    __syncthreads();  // barB: pred + ubuf visible

    // ---- update: thread (ub, un), tid < 256; publish fused word ----
    if (tid < 256) {
      float pre = 0.f;
      #pragma unroll
      for (int q = 0; q < 16; ++q) pre += pred[q][ub][un];
      #pragma unroll
      for (int j = 0; j < NIN; ++j)
        pre = fmaf(ubuf[par][ub][j], winp_s[un][j], pre);
      const float sn = 0.9f * scur + 0.1f * (fmaxf(pre, 0.f) + rnv);
      states[((size_t)(g * GG + ub) * TT + t + 1) * NN + ung] = sn;
      const u64 pw = ((u64)(unsigned)(t + 1) << 32) | __float_as_uint(sn);
      xst(&xbuf[(((size_t)((t + 1) & 1) * NGRP + g) * GG + ub) * NN + ung], pw);
      asm volatile("" ::: "memory");  // publish not reordered past polls
      s_all[ub][ung] = sn;
      scur = sn;
    }

    // ---- prefetch next step's poll words (issue now, wait at use) ----
    // Peers publish tag t+1 into parity (t+1)&1 around this same time;
    // the ~1us flight overlaps the loop tail. Stale result just fails
    // the tag check above (self-validating) -> blocking re-poll.
    if (tid < 384) {
      const u64* ppn = ((t + 1) & 1) ? pp1 : pp0;
      pfa = xld(ppn);
      pfb = xld(ppn + 1);
    }
    asm volatile("" ::: "memory");  // pin issue point (no sinking to use)
    // no trailing barrier: next fetch writes peer LDS slices (disjoint
    // from own-slice update writes); pred overwrite fenced by barA+barB.
  }
}

// outputs[b][t] = dot(states[b][t][:], Wout) -- one wave per row
__global__ __launch_bounds__(256)
void out_proj(const float* __restrict__ states, const float* __restrict__ Wout,
              float* __restrict__ outputs) {
  const int lane = threadIdx.x & 63;
  const size_t row = (size_t)blockIdx.x * 4 + (threadIdx.x >> 6);
  if (row >= (size_t)BB * TT) return;
  const float* sr = states + row * NN;
  float acc = 0.f;
  #pragma unroll
  for (int h = 0; h < 2; ++h) {
    const float4 sv = *reinterpret_cast<const float4*>(sr + h * 256 + lane * 4);
    const float4 wv = *reinterpret_cast<const float4*>(Wout + h * 256 + lane * 4);
    acc = fmaf(sv.x, wv.x, acc);
    acc = fmaf(sv.y, wv.y, acc);
    acc = fmaf(sv.z, wv.z, acc);
    acc = fmaf(sv.w, wv.w, acc);
  }
  acc = wave_sum(acc);
  if (lane == 0) outputs[row] = acc;
}

// ---------------- fallback: proven R1 kernel (ws too small) ----------------
__global__ __launch_bounds__(512)
void rnn_fused(const float* __restrict__ u, const float* __restrict__ rnz,
               const float* __restrict__ inz, const float* __restrict__ Wsrc,
               const float* __restrict__ Winp, const float* __restrict__ Wout,
               const float* __restrict__ yinit,
               float* __restrict__ states, float* __restrict__ outputs) {
  const int tid = threadIdx.x;
  const int n4 = tid & 127;
  const int kc = tid >> 7;
  const int b0 = blockIdx.x * 2;
  const int b1 = b0 + 1;

  __shared__ __align__(16) float s[2][NN];
  __shared__ __align__(16) float red[2][128][20];
  __shared__ float ubf[2 * NIN];
  __shared__ float outred[2][8];

  float wi[NIN];
  #pragma unroll
  for (int j = 0; j < NIN; ++j) wi[j] = Winp[tid * NIN + j];
  const float wo = Wout[tid];
  const float yv = yinit[tid];

  s[0][tid] = yv;
  s[1][tid] = yv;
  states[(size_t)(b0 * TT) * NN + tid] = yv;
  states[(size_t)(b1 * TT) * NN + tid] = yv;
  {
    float pzz = wave_sum(yv * wo);
    if ((tid & 63) == 0) outred[0][tid >> 6] = pzz;
  }
  __syncthreads();
  if (tid < 2) {
    float a = 0.f;
    #pragma unroll
    for (int wq = 0; wq < 8; ++wq) a += outred[0][wq];
    outputs[(tid ? b1 : b0) * TT] = a;
  }
  __syncthreads();

  for (int t = 0; t < TT - 1; ++t) {
    const float rn0 = rnz[(size_t)(b0 * TT + t) * NN + tid];
    const float rn1 = rnz[(size_t)(b1 * TT + t) * NN + tid];
    float uv = 0.f;
    if (tid < 2 * NIN) {
      const int b = (tid < NIN) ? b0 : b1;
      const int j = (tid < NIN) ? tid : tid - NIN;
      const int idx = (b * TT + t) * NIN + j;
      uv = u[idx] + inz[idx];
    }
    float a0[4] = {0.f, 0.f, 0.f, 0.f};
    float a1[4] = {0.f, 0.f, 0.f, 0.f};
    const int kbase0 = kc * 128;
    #pragma unroll 4
    for (int j4 = 0; j4 < 32; ++j4) {
      const int kb = kbase0 + j4 * 4;
      const float4 s0v = *reinterpret_cast<const float4*>(&s[0][kb]);
      const float4 s1v = *reinterpret_cast<const float4*>(&s[1][kb]);
      const float s0a[4] = {s0v.x, s0v.y, s0v.z, s0v.w};
      const float s1a[4] = {s1v.x, s1v.y, s1v.z, s1v.w};
      #pragma unroll
      for (int jj = 0; jj < 4; ++jj) {
        const int k = kb + jj;
        const float* pw = Wsrc + (size_t)(n4 << 2) * NN + k;
        float4 wv;
        wv.x = pw[0]; wv.y = pw[NN]; wv.z = pw[2 * NN]; wv.w = pw[3 * NN];
        a0[0] = fmaf(wv.x, s0a[jj], a0[0]);
        a0[1] = fmaf(wv.y, s0a[jj], a0[1]);
        a0[2] = fmaf(wv.z, s0a[jj], a0[2]);
        a0[3] = fmaf(wv.w, s0a[jj], a0[3]);
        a1[0] = fmaf(wv.x, s1a[jj], a1[0]);
        a1[1] = fmaf(wv.y, s1a[jj], a1[1]);
        a1[2] = fmaf(wv.z, s1a[jj], a1[2]);
        a1[3] = fmaf(wv.w, s1a[jj], a1[3]);
      }
    }
    if (tid < 2 * NIN) ubf[tid] = uv;
    *reinterpret_cast<float4*>(&red[0][n4][kc << 2]) =
        make_float4(a0[0], a0[1], a0[2], a0[3]);
    *reinterpret_cast<float4*>(&red[1][n4][kc << 2]) =
        make_float4(a1[0], a1[1], a1[2], a1[3]);
    __syncthreads();
    const int n = tid;
    const int r = n >> 2, c = n & 3;
    float pre0 = (red[0][r][c] + red[0][r][4 + c]) +
                 (red[0][r][8 + c] + red[0][r][12 + c]);
    float pre1 = (red[1][r][c] + red[1][r][4 + c]) +
                 (red[1][r][8 + c] + red[1][r][12 + c]);
    #pragma unroll
    for (int j = 0; j < NIN; ++j) {
      pre0 = fmaf(ubf[j], wi[j], pre0);
      pre1 = fmaf(ubf[NIN + j], wi[j], pre1);
    }
    const float sn0 = 0.9f * s[0][n] + 0.1f * (fmaxf(pre0, 0.f) + rn0);
    const float sn1 = 0.9f * s[1][n] + 0.1f * (fmaxf(pre1, 0.f) + rn1);
    states[(size_t)(b0 * TT + t + 1) * NN + n] = sn0;
    states[(size_t)(b1 * TT + t + 1) * NN + n] = sn1;
    s[0][n] = sn0;
    s[1][n] = sn1;
    float p0 = wave_sum(sn0 * wo);
    float p1 = wave_sum(sn1 * wo);
    if ((tid & 63) == 0) {
      outred[0][tid >> 6] = p0;
      outred[1][tid >> 6] = p1;
    }
    __syncthreads();
    if (tid < 2) {
      float a = 0.f;
      #pragma unroll
      for (int wq = 0; wq < 8; ++wq) a += outred[tid][wq];
      outputs[(tid ? b1 : b0) * TT + t + 1] = a;
    }
  }
}

extern "C" void kernel_launch(void* const* d_in, const int* in_sizes, int n_in,
                              void* d_out, int out_size, void* d_ws, size_t ws_size,
                              hipStream_t stream) {
  const float* u    = (const float*)d_in[0];
  const float* rnz  = (const float*)d_in[1];
  const float* inz  = (const float*)d_in[2];
  const float* Wrec = (const float*)d_in[3];
  const float* Winp = (const float*)d_in[4];
  const float* Wout = (const float*)d_in[5];
  const float* yin  = (const float*)d_in[6];
  float* states  = (float*)d_out;
  float* outputs = states + (size_t)BB * TT * NN;

  if (ws_size >= WS_NEED) {
    u64* xbuf = (u64*)d_ws;
    init_xbuf<<<(XWORDS + 255) / 256, 256, 0, stream>>>(xbuf);
    rnn_tagx6<<<NWG, 512, 0, stream>>>(u, rnz, inz, Wrec, Winp, yin,
                                       states, xbuf);
    out_proj<<<(BB * TT + 3) / 4, 256, 0, stream>>>(states, Wout, outputs);
  } else {
    rnn_fused<<<BB / 2, 512, 0, stream>>>(u, rnz, inz, Wrec, Winp, Wout,
                                          yin, states, outputs);
  }
}

// Round 20
// 2618.082 us; speedup vs baseline: 1.1260x; 1.1260x over previous
//
#include <hip/hip_runtime.h>

// RNN: s_{t+1} = 0.9*s + 0.1*(relu(s@Wrec^T + (u+inz)@Winp^T) + rn)
// d_out = states (B,T,N) fp32 then outputs (B,T,1) fp32, flat-concat.
//
// FINAL (= R18, best measured 2.63 ms): resident-W, n-partitioned,
// fused tag+payload IF exchange with paired polls.
//   Journey: R1 streamed-W 8.09ms (per-CU L2 BW wall) -> R9 IF-sync
//   4.06 -> R12 fused tag+payload 2.99 -> R15 GG=2 2.86 -> R18 paired
//   polls 2.63. Dead ends (measured): L2-scope exchange (R11 hang, R16
//   never-validates), skew (R13 +0.4ms), poll prefetch (R19 +0.3ms:
//   stores need ~1us to become observable), 1024-thr resident-W (R14:
//   allocator caps at 64 VGPR -> spill).
//   Structural floor: 999 serial cross-WG exchanges x (~1.3us IF
//   visibility + ~0.95us compute/update/barriers) ~= 2.3-2.5 ms; this
//   kernel sits ~8-12% above it. Not a BW/compute roofline (HBM 5.7%,
//   VALU 38% active): a latency floor.
// Design:
//   - PP=4 n-slices x 64 groups x GG=2 batches; 256 WGs x 512 thr.
//   - WG p holds W[slice p][all k] in VGPRs (128 floats/thread), pinned
//     live by in-loop scalar asm "+v" (unpinned W gets re-streamed).
//   - Exchange word = (tag<<32 | fp32), system-scope relaxed atomics
//     (sc0sc1 -> IF, chip-coherent; no cache maintenance). Readers poll
//     PAIRS via 16B dwordx4 sc0 sc1 loads; each 8B half self-validates
//     via its tag (atomic writer halves; aligned 16B read can't tear).
//   - xbuf parity double-buffer, WAR-safe 2-deep; tags monotone; init
//     kernel resets tags each call (0xAA poison parses negative) ->
//     graph-replay-safe. 2 barriers/step.
// out_proj projects outputs afterwards. Fallback R1-style kernel if ws
// is too small (< 1 MB).

#define NN 512
#define BB 128
#define TT 1000
#define NIN 6
#define PP 4                    // n-slices (WGs per group)
#define GG 2                    // batches per group
#define NGRP (BB / GG)          // 64 groups
#define NWG (PP * NGRP)         // 256 workgroups
#define SLICE (NN / PP)         // 128
#define XWORDS (2 * NGRP * GG * NN)          // 131072 words = 1 MB
#define WS_NEED (XWORDS * sizeof(unsigned long long))

typedef unsigned long long u64;
typedef unsigned int u32x4 __attribute__((ext_vector_type(4)));

__global__ void init_xbuf(u64* xbuf) {
  const int i = blockIdx.x * 256 + threadIdx.x;
  if (i < XWORDS) xbuf[i] = 0xFFFFFFFF00000000ULL;  // tag = -1
}

__device__ __forceinline__ float wave_sum(float v) {
  #pragma unroll
  for (int off = 32; off > 0; off >>= 1) v += __shfl_xor(v, off, 64);
  return v;
}

// empty asm with tied SCALAR outputs: values become opaque (non-remat).
__device__ __forceinline__ void pin4(float4& a, float4& b, float4& c, float4& d) {
  asm volatile("" : "+v"(a.x), "+v"(a.y), "+v"(a.z), "+v"(a.w),
                    "+v"(b.x), "+v"(b.y), "+v"(b.z), "+v"(b.w),
                    "+v"(c.x), "+v"(c.y), "+v"(c.z), "+v"(c.w),
                    "+v"(d.x), "+v"(d.y), "+v"(d.z), "+v"(d.w));
}

// system-scope relaxed u64 store (sc0sc1 -> IF, chip-coherent).
__device__ __forceinline__ void xst(u64* p, u64 v) {
  __hip_atomic_store(p, v, __ATOMIC_RELAXED, __HIP_MEMORY_SCOPE_SYSTEM);
}
// paired poll: 16B system-scope load of two adjacent fused words.
// v.x/v.y = payload/tag of word0; v.z/v.w = payload/tag of word1.
__device__ __forceinline__ u32x4 xld4(const u64* p) {
  u32x4 v;
  asm volatile("global_load_dwordx4 %0, %1, off sc0 sc1\n\ts_waitcnt vmcnt(0)"
               : "=v"(v) : "v"(p) : "memory");
  return v;
}

__global__ __launch_bounds__(512, 1)
void rnn_tagx5(const float* __restrict__ u, const float* __restrict__ rnz,
               const float* __restrict__ inz, const float* __restrict__ Wrec,
               const float* __restrict__ Winp, const float* __restrict__ yinit,
               float* __restrict__ states, u64* __restrict__ xbuf) {
  const int tid = threadIdx.x;
  // bid remap: group's 4 WGs share bid&7 (locality hint only; protocol
  // is placement-independent -- all exchange goes through IF).
  const int xcd = blockIdx.x & 7;
  const int rest = blockIdx.x >> 3;     // 0..31
  const int p = rest & 3;               // my n-slice
  const int g = (rest >> 2) * 8 + xcd;  // my group 0..63

  // phase-A mapping: thread (nq, ks) = 4 n-rows x 32-k window x 2 batches
  const int nq = tid & 31;
  const int n0 = nq << 2;               // local n base
  const int ks = tid >> 5;              // k-split 0..15 (wave-uniform x2)
  const int k0 = ks << 5;               // global k base
  // update mapping (tid < 256): thread = (batch, local n)
  const int ub = (tid >> 7) & 1;
  const int un = tid & 127;
  const int ung = p * SLICE + un;

  __shared__ __align__(16) float pred[16][GG][SLICE];  // 16 KB
  __shared__ __align__(16) float s_all[GG][NN];        // 4 KB
  __shared__ float winp_s[SLICE][NIN];                 // 3 KB
  __shared__ float ubuf[2][GG][NIN];                   // parity-buffered

  // ---- one-time: W fragment (4 rows x 32 k), Winp ----
  float4 w[4][8];
  #pragma unroll
  for (int i = 0; i < 4; ++i) {
    const float* wr = Wrec + (size_t)(p * SLICE + n0 + i) * NN + k0;
    #pragma unroll
    for (int q = 0; q < 8; ++q)
      w[i][q] = *reinterpret_cast<const float4*>(wr + 4 * q);
  }
  for (int i = tid; i < SLICE * NIN; i += 512) {
    const int r = i / NIN, j = i - r * NIN;
    winp_s[r][j] = Winp[(p * SLICE + r) * NIN + j];
  }
  // s_0 = y_init everywhere (local knowledge: no exchange needed at t=0)
  for (int i = tid; i < GG * NN; i += 512)
    s_all[i >> 9][i & 511] = yinit[i & 511];
  for (int i = tid; i < GG * NN; i += 512)
    states[(size_t)(g * GG + (i >> 9)) * TT * NN + (i & 511)] = yinit[i & 511];
  float scur = (tid < 256) ? yinit[ung] : 0.f;
  __syncthreads();

  for (int t = 0; t < TT - 1; ++t) {
    const int par = t & 1;

    // pin W live (unpinned W gets re-streamed from L2 every step)
    #pragma unroll
    for (int i = 0; i < 4; ++i) {
      pin4(w[i][0], w[i][1], w[i][2], w[i][3]);
      pin4(w[i][4], w[i][5], w[i][6], w[i][7]);
    }

    // early per-step loads (plain, cached; consumed after barB)
    float rnv = 0.f;
    if (tid < 256)
      rnv = rnz[((size_t)(g * GG + ub) * TT + t) * NN + ung];
    if (tid < GG * NIN) {
      const int b = tid / NIN, j = tid - b * NIN;
      const size_t idx = ((size_t)(g * GG + b) * TT + t) * NIN + j;
      ubuf[par][b][j] = u[idx] + inz[idx];
    }

    // ---- fetch: paired poll of fused (tag|payload) words, 3 slices ----
    // 384 pairs: rank r = tid>>7 selects peer slice q=(p+1+r)&3;
    // rem = tid&127: batch = rem>>6, n-pair = (rem&63)*2.
    if (t > 0 && tid < 384) {
      const int fq = (p + 1 + (tid >> 7)) & 3;
      const int rem = tid & 127;
      const int fb = rem >> 6;
      const int fn = (rem & 63) << 1;
      const u64* pp = xbuf + ((size_t)par * NGRP + g) * GG * NN +
                      (size_t)fb * NN + fq * SLICE + fn;
      u32x4 v = xld4(pp);
      while ((int)v.y < t || (int)v.w < t) {
        __builtin_amdgcn_s_sleep(1);
        v = xld4(pp);
      }
      *reinterpret_cast<float2*>(&s_all[fb][fq * SLICE + fn]) =
          make_float2(__uint_as_float(v.x), __uint_as_float(v.z));
    }
    __syncthreads();  // barA: s_all complete (own slice from last update)

    // ---- phase A: 4 n x 32 k x 2 b partial dots (256 fmaf) ----
    float a0[GG], a1[GG], a2[GG], a3[GG];
    #pragma unroll
    for (int b = 0; b < GG; ++b) { a0[b] = 0.f; a1[b] = 0.f; a2[b] = 0.f; a3[b] = 0.f; }
    #pragma unroll
    for (int b = 0; b < GG; ++b) {
      #pragma unroll
      for (int q = 0; q < 8; ++q) {
        const float4 sv = *reinterpret_cast<const float4*>(&s_all[b][k0 + 4 * q]);
        a0[b] = fmaf(w[0][q].x, sv.x, a0[b]); a0[b] = fmaf(w[0][q].y, sv.y, a0[b]);
        a0[b] = fmaf(w[0][q].z, sv.z, a0[b]); a0[b] = fmaf(w[0][q].w, sv.w, a0[b]);
        a1[b] = fmaf(w[1][q].x, sv.x, a1[b]); a1[b] = fmaf(w[1][q].y, sv.y, a1[b]);
        a1[b] = fmaf(w[1][q].z, sv.z, a1[b]); a1[b] = fmaf(w[1][q].w, sv.w, a1[b]);
        a2[b] = fmaf(w[2][q].x, sv.x, a2[b]); a2[b] = fmaf(w[2][q].y, sv.y, a2[b]);
        a2[b] = fmaf(w[2][q].z, sv.z, a2[b]); a2[b] = fmaf(w[2][q].w, sv.w, a2[b]);
        a3[b] = fmaf(w[3][q].x, sv.x, a3[b]); a3[b] = fmaf(w[3][q].y, sv.y, a3[b]);
        a3[b] = fmaf(w[3][q].z, sv.z, a3[b]); a3[b] = fmaf(w[3][q].w, sv.w, a3[b]);
      }
    }
    #pragma unroll
    for (int b = 0; b < GG; ++b)
      *reinterpret_cast<float4*>(&pred[ks][b][n0]) =
          make_float4(a0[b], a1[b], a2[b], a3[b]);
    __syncthreads();  // barB: pred + ubuf visible

    // ---- update: thread (ub, un), tid < 256; publish fused word ----
    if (tid < 256) {
      float pre = 0.f;
      #pragma unroll
      for (int q = 0; q < 16; ++q) pre += pred[q][ub][un];
      #pragma unroll
      for (int j = 0; j < NIN; ++j)
        pre = fmaf(ubuf[par][ub][j], winp_s[un][j], pre);
      const float sn = 0.9f * scur + 0.1f * (fmaxf(pre, 0.f) + rnv);
      states[((size_t)(g * GG + ub) * TT + t + 1) * NN + ung] = sn;
      const u64 pw = ((u64)(unsigned)(t + 1) << 32) | __float_as_uint(sn);
      xst(&xbuf[(((size_t)((t + 1) & 1) * NGRP + g) * GG + ub) * NN + ung], pw);
      asm volatile("" ::: "memory");  // publish not reordered past polls
      s_all[ub][ung] = sn;
      scur = sn;
    }
    // no trailing barrier: next fetch writes peer LDS slices (disjoint
    // from own-slice update writes); pred overwrite fenced by barA+barB.
  }
}

// outputs[b][t] = dot(states[b][t][:], Wout) -- one wave per row
__global__ __launch_bounds__(256)
void out_proj(const float* __restrict__ states, const float* __restrict__ Wout,
              float* __restrict__ outputs) {
  const int lane = threadIdx.x & 63;
  const size_t row = (size_t)blockIdx.x * 4 + (threadIdx.x >> 6);
  if (row >= (size_t)BB * TT) return;
  const float* sr = states + row * NN;
  float acc = 0.f;
  #pragma unroll
  for (int h = 0; h < 2; ++h) {
    const float4 sv = *reinterpret_cast<const float4*>(sr + h * 256 + lane * 4);
    const float4 wv = *reinterpret_cast<const float4*>(Wout + h * 256 + lane * 4);
    acc = fmaf(sv.x, wv.x, acc);
    acc = fmaf(sv.y, wv.y, acc);
    acc = fmaf(sv.z, wv.z, acc);
    acc = fmaf(sv.w, wv.w, acc);
  }
  acc = wave_sum(acc);
  if (lane == 0) outputs[row] = acc;
}

// ---------------- fallback: proven R1 kernel (ws too small) ----------------
__global__ __launch_bounds__(512)
void rnn_fused(const float* __restrict__ u, const float* __restrict__ rnz,
               const float* __restrict__ inz, const float* __restrict__ Wsrc,
               const float* __restrict__ Winp, const float* __restrict__ Wout,
               const float* __restrict__ yinit,
               float* __restrict__ states, float* __restrict__ outputs) {
  const int tid = threadIdx.x;
  const int n4 = tid & 127;
  const int kc = tid >> 7;
  const int b0 = blockIdx.x * 2;
  const int b1 = b0 + 1;

  __shared__ __align__(16) float s[2][NN];
  __shared__ __align__(16) float red[2][128][20];
  __shared__ float ubf[2 * NIN];
  __shared__ float outred[2][8];

  float wi[NIN];
  #pragma unroll
  for (int j = 0; j < NIN; ++j) wi[j] = Winp[tid * NIN + j];
  const float wo = Wout[tid];
  const float yv = yinit[tid];

  s[0][tid] = yv;
  s[1][tid] = yv;
  states[(size_t)(b0 * TT) * NN + tid] = yv;
  states[(size_t)(b1 * TT) * NN + tid] = yv;
  {
    float pzz = wave_sum(yv * wo);
    if ((tid & 63) == 0) outred[0][tid >> 6] = pzz;
  }
  __syncthreads();
  if (tid < 2) {
    float a = 0.f;
    #pragma unroll
    for (int wq = 0; wq < 8; ++wq) a += outred[0][wq];
    outputs[(tid ? b1 : b0) * TT] = a;
  }
  __syncthreads();

  for (int t = 0; t < TT - 1; ++t) {
    const float rn0 = rnz[(size_t)(b0 * TT + t) * NN + tid];
    const float rn1 = rnz[(size_t)(b1 * TT + t) * NN + tid];
    float uv = 0.f;
    if (tid < 2 * NIN) {
      const int b = (tid < NIN) ? b0 : b1;
      const int j = (tid < NIN) ? tid : tid - NIN;
      const int idx = (b * TT + t) * NIN + j;
      uv = u[idx] + inz[idx];
    }
    float a0[4] = {0.f, 0.f, 0.f, 0.f};
    float a1[4] = {0.f, 0.f, 0.f, 0.f};
    const int kbase0 = kc * 128;
    #pragma unroll 4
    for (int j4 = 0; j4 < 32; ++j4) {
      const int kb = kbase0 + j4 * 4;
      const float4 s0v = *reinterpret_cast<const float4*>(&s[0][kb]);
      const float4 s1v = *reinterpret_cast<const float4*>(&s[1][kb]);
      const float s0a[4] = {s0v.x, s0v.y, s0v.z, s0v.w};
      const float s1a[4] = {s1v.x, s1v.y, s1v.z, s1v.w};
      #pragma unroll
      for (int jj = 0; jj < 4; ++jj) {
        const int k = kb + jj;
        const float* pw = Wsrc + (size_t)(n4 << 2) * NN + k;
        float4 wv;
        wv.x = pw[0]; wv.y = pw[NN]; wv.z = pw[2 * NN]; wv.w = pw[3 * NN];
        a0[0] = fmaf(wv.x, s0a[jj], a0[0]);
        a0[1] = fmaf(wv.y, s0a[jj], a0[1]);
        a0[2] = fmaf(wv.z, s0a[jj], a0[2]);
        a0[3] = fmaf(wv.w, s0a[jj], a0[3]);
        a1[0] = fmaf(wv.x, s1a[jj], a1[0]);
        a1[1] = fmaf(wv.y, s1a[jj], a1[1]);
        a1[2] = fmaf(wv.z, s1a[jj], a1[2]);
        a1[3] = fmaf(wv.w, s1a[jj], a1[3]);
      }
    }
    if (tid < 2 * NIN) ubf[tid] = uv;
    *reinterpret_cast<float4*>(&red[0][n4][kc << 2]) =
        make_float4(a0[0], a0[1], a0[2], a0[3]);
    *reinterpret_cast<float4*>(&red[1][n4][kc << 2]) =
        make_float4(a1[0], a1[1], a1[2], a1[3]);
    __syncthreads();
    const int n = tid;
    const int r = n >> 2, c = n & 3;
    float pre0 = (red[0][r][c] + red[0][r][4 + c]) +
                 (red[0][r][8 + c] + red[0][r][12 + c]);
    float pre1 = (red[1][r][c] + red[1][r][4 + c]) +
                 (red[1][r][8 + c] + red[1][r][12 + c]);
    #pragma unroll
    for (int j = 0; j < NIN; ++j) {
      pre0 = fmaf(ubf[j], wi[j], pre0);
      pre1 = fmaf(ubf[NIN + j], wi[j], pre1);
    }
    const float sn0 = 0.9f * s[0][n] + 0.1f * (fmaxf(pre0, 0.f) + rn0);
    const float sn1 = 0.9f * s[1][n] + 0.1f * (fmaxf(pre1, 0.f) + rn1);
    states[(size_t)(b0 * TT + t + 1) * NN + n] = sn0;
    states[(size_t)(b1 * TT + t + 1) * NN + n] = sn1;
    s[0][n] = sn0;
    s[1][n] = sn1;
    float p0 = wave_sum(sn0 * wo);
    float p1 = wave_sum(sn1 * wo);
    if ((tid & 63) == 0) {
      outred[0][tid >> 6] = p0;
      outred[1][tid >> 6] = p1;
    }
    __syncthreads();
    if (tid < 2) {
      float a = 0.f;
      #pragma unroll
      for (int wq = 0; wq < 8; ++wq) a += outred[tid][wq];
      outputs[(tid ? b1 : b0) * TT + t + 1] = a;
    }
  }
}

extern "C" void kernel_launch(void* const* d_in, const int* in_sizes, int n_in,
                              void* d_out, int out_size, void* d_ws, size_t ws_size,
                              hipStream_t stream) {
  const float* u    = (const float*)d_in[0];
  const float* rnz  = (const float*)d_in[1];
  const float* inz  = (const float*)d_in[2];
  const float* Wrec = (const float*)d_in[3];
  const float* Winp = (const float*)d_in[4];
  const float* Wout = (const float*)d_in[5];
  const float* yin  = (const float*)d_in[6];
  float* states  = (float*)d_out;
  float* outputs = states + (size_t)BB * TT * NN;

  if (ws_size >= WS_NEED) {
    u64* xbuf = (u64*)d_ws;
    init_xbuf<<<(XWORDS + 255) / 256, 256, 0, stream>>>(xbuf);
    rnn_tagx5<<<NWG, 512, 0, stream>>>(u, rnz, inz, Wrec, Winp, yin,
                                       states, xbuf);
    out_proj<<<(BB * TT + 3) / 4, 256, 0, stream>>>(states, Wout, outputs);
  } else {
    rnn_fused<<<BB / 2, 512, 0, stream>>>(u, rnz, inz, Wrec, Winp, Wout,
                                          yin, states, outputs);
  }
}